// Round 4
// baseline (19.038 us; speedup 1.0000x reference)
//
#include <hip/hip_runtime.h>

// Soft polygon rasterization (mode=mask), B=128, N=64, W=H=64.
// R4: packed-fp32 (VOP3P v_pk_*_f32) inner loop via inline asm — 2 px per
// instruction slot; edge-constant broadcasts via op_sel half-selects (free).
// Geometry = R1 (best measured): 512 blocks x 256 thr, 4 px/thread in-row,
// float4 store. Edge records in LDS, broadcast ds_read_b128 (conflict-free).
// Crossing parity via __ballot + scalar-pipe xor. min fold via v_min3.

typedef float f32x2 __attribute__((ext_vector_type(2)));
typedef float f32x4 __attribute__((ext_vector_type(4)));

// d = a*b + c (packed)
#define PK_FMA(d,a,b,c)      asm("v_pk_fma_f32 %0, %1, %2, %3" : "=v"(d) : "v"(a), "v"(b), "v"(c))
#define PK_MUL(d,a,b)        asm("v_pk_mul_f32 %0, %1, %2" : "=v"(d) : "v"(a), "v"(b))
// d = a*bc(B.lo) + c
#define PK_FMA_BLO(d,a,B,c)  asm("v_pk_fma_f32 %0, %1, %2, %3 op_sel_hi:[1,0,1]" : "=v"(d) : "v"(a), "v"(B), "v"(c))
// d = -a*bc(B.lo) + c
#define PK_NFMA_BLO(d,a,B,c) asm("v_pk_fma_f32 %0, %1, %2, %3 op_sel_hi:[1,0,1] neg_lo:[1,0,0] neg_hi:[1,0,0]" : "=v"(d) : "v"(a), "v"(B), "v"(c))
// d = -a*bc(B.hi) + c
#define PK_NFMA_BHI(d,a,B,c) asm("v_pk_fma_f32 %0, %1, %2, %3 op_sel:[0,1,0] op_sel_hi:[1,1,1] neg_lo:[1,0,0] neg_hi:[1,0,0]" : "=v"(d) : "v"(a), "v"(B), "v"(c))
// d = a - bc(B.lo)
#define PK_SUB_BLO(d,a,B)    asm("v_pk_add_f32 %0, %1, %2 op_sel_hi:[1,0] neg_lo:[0,1] neg_hi:[0,1]" : "=v"(d) : "v"(a), "v"(B))
// d = a - bc(B.hi)
#define PK_SUB_BHI(d,a,B)    asm("v_pk_add_f32 %0, %1, %2 op_sel:[0,1] op_sel_hi:[1,1] neg_lo:[0,1] neg_hi:[0,1]" : "=v"(d) : "v"(a), "v"(B))
// d = a * bc(B.hi)
#define PK_MUL_BHI(d,a,B)    asm("v_pk_mul_f32 %0, %1, %2 op_sel:[0,1] op_sel_hi:[1,1]" : "=v"(d) : "v"(a), "v"(B))

// E0 = {ax, ay, dx, dy}, E1 = {dx/dd, dy/dd, dx/dy, by}
// outputs: DA = d2 for (px0,px1), DB = d2 for (px2,px3)
#define EDGE(E0, E1, DA, DB)                                        \
    {                                                               \
        f32x2 E0lo = E0.xy, E0hi = E0.zw, E1lo = E1.xy;             \
        f32x2 payv, pdyrv;                                          \
        PK_SUB_BHI(payv, pyv, E0lo);        /* pay = py - ay   */   \
        PK_MUL_BHI(pdyrv, payv, E1lo);      /* pay * (dy/dd)   */   \
        float xint = fmaf(payv.x, E1.z, E0.x);                      \
        bool  cond = (E0.y > py) != (E1.w > py);                    \
        f32x2 paxA, paxB, tA, tB, exA, exB, eyA, eyB, qA, qB;       \
        PK_SUB_BLO(paxA, pxA, E0lo);        /* px - ax         */   \
        PK_SUB_BLO(paxB, pxB, E0lo);                                \
        PK_FMA_BLO(tA, paxA, E1lo, pdyrv);  /* dot(pa,d)/dd    */   \
        PK_FMA_BLO(tB, paxB, E1lo, pdyrv);                          \
        tA.x = fminf(fmaxf(tA.x, 0.0f), 1.0f);  /* v_med3 */        \
        tA.y = fminf(fmaxf(tA.y, 0.0f), 1.0f);                      \
        tB.x = fminf(fmaxf(tB.x, 0.0f), 1.0f);                      \
        tB.y = fminf(fmaxf(tB.y, 0.0f), 1.0f);                      \
        PK_NFMA_BLO(exA, tA, E0hi, paxA);   /* pax - t*dx      */   \
        PK_NFMA_BLO(exB, tB, E0hi, paxB);                           \
        PK_NFMA_BHI(eyA, tA, E0hi, payv);   /* pay - t*dy      */   \
        PK_NFMA_BHI(eyB, tB, E0hi, payv);                           \
        PK_MUL(qA, eyA, eyA);                                       \
        PK_MUL(qB, eyB, eyB);                                       \
        PK_FMA(DA, exA, exA, qA);           /* d2              */   \
        PK_FMA(DB, exB, exB, qB);                                   \
        pm0 ^= __ballot(cond && (px0f < xint));                     \
        pm1 ^= __ballot(cond && (px1f < xint));                     \
        pm2 ^= __ballot(cond && (px2f < xint));                     \
        pm3 ^= __ballot(cond && (px3f < xint));                     \
    }

__global__ __launch_bounds__(256) void softpoly_kernel(
    const float* __restrict__ verts, float* __restrict__ out)
{
    __shared__ f32x4 e0[64];  // ax, ay, dx, dy
    __shared__ f32x4 e1[64];  // dx/dd, dy/dd, dx/dy, by

    const int tid = threadIdx.x;
    const int b   = blockIdx.x >> 2;

    if (tid < 64) {
        const float2* vp = (const float2*)(verts + (b << 7));
        float2 a = vp[tid];
        float2 c = vp[(tid + 1) & 63];
        float dx = c.x - a.x, dy = c.y - a.y;
        float dd = fmaxf(fmaf(dx, dx, dy * dy), 1e-12f);
        float rdd = 1.0f / dd;
        e0[tid] = (f32x4){a.x, a.y, dx, dy};
        e1[tid] = (f32x4){dx * rdd, dy * rdd, dx / dy, c.y};
    }
    __syncthreads();

    const int row = ((blockIdx.x & 3) << 4) + (tid >> 4);  // 0..63
    const float py   = (float)row;
    const float px0f = (float)((tid & 15) << 2);
    const float px1f = px0f + 1.0f, px2f = px0f + 2.0f, px3f = px0f + 3.0f;
    const f32x2 pyv = {py, py};
    const f32x2 pxA = {px0f, px1f}, pxB = {px2f, px3f};

    float md0 = 1e30f, md1 = 1e30f, md2 = 1e30f, md3 = 1e30f;
    unsigned long long pm0 = 0ull, pm1 = 0ull, pm2 = 0ull, pm3 = 0ull;

    #pragma unroll 2
    for (int n = 0; n < 64; n += 2) {
        const f32x4 A0 = e0[n],     A1 = e1[n];
        const f32x4 B0 = e0[n + 1], B1 = e1[n + 1];
        f32x2 dAA, dAB, dBA, dBB;
        EDGE(A0, A1, dAA, dAB)
        EDGE(B0, B1, dBA, dBB)
        md0 = fminf(md0, fminf(dAA.x, dBA.x));  // v_min3_f32
        md1 = fminf(md1, fminf(dAA.y, dBA.y));
        md2 = fminf(md2, fminf(dAB.x, dBB.x));
        md3 = fminf(md3, fminf(dAB.y, dBB.y));
    }

    const int lane = tid & 63;
    const float s0 = ((pm0 >> lane) & 1ull) ? 10.0f : -10.0f;
    const float s1 = ((pm1 >> lane) & 1ull) ? 10.0f : -10.0f;
    const float s2 = ((pm2 >> lane) & 1ull) ? 10.0f : -10.0f;
    const float s3 = ((pm3 >> lane) & 1ull) ? 10.0f : -10.0f;
    float4 r;
    r.x = 1.0f / (1.0f + __expf(-s0 * md0));
    r.y = 1.0f / (1.0f + __expf(-s1 * md1));
    r.z = 1.0f / (1.0f + __expf(-s2 * md2));
    r.w = 1.0f / (1.0f + __expf(-s3 * md3));
    ((float4*)out)[(b << 10) + (row << 4) + (tid & 15)] = r;
}

extern "C" void kernel_launch(void* const* d_in, const int* in_sizes, int n_in,
                              void* d_out, int out_size, void* d_ws, size_t ws_size,
                              hipStream_t stream) {
    const float* verts = (const float*)d_in[0];
    float* out = (float*)d_out;
    const int B = out_size >> 12;  // 64*64 px per image
    softpoly_kernel<<<dim3(B * 4), dim3(256), 0, stream>>>(verts, out);
}

// Round 5
// 15.211 us; speedup vs baseline: 1.2516x; 1.2516x over previous
//
#include <hip/hip_runtime.h>

// Soft polygon rasterization (mode=mask), B=128, N=64, W=H=64.
// R5 = merge of proven-best pieces, plain HIP (no asm):
//   - R1 geometry: 512 blocks x 256 thr, one batch x 16-row chunk per block,
//     4 consecutive x px per thread -> float4 store (best measured; halves
//     LDS read traffic vs 2px/thread).
//   - R3 records: premultiplied (dx/dd, dy/dd, dx/dy) so per-px t is ONE fma.
//   - Crossing parity via __ballot masks: per edge 2 v_cmp + s_xor (shared),
//     per px 1 v_cmp + s_and/s_xor on the scalar pipe.
//   - Explicit fmed3 clamp; pairwise min fold -> v_min3_f32.
// Per-edge VALU/thread ~39 vs R1's ~45.

typedef unsigned long long u64;

__global__ __launch_bounds__(256, 2) void softpoly_kernel(
    const float* __restrict__ verts, float* __restrict__ out)
{
    __shared__ float4 e0[64];  // ax, ay, dx, dy
    __shared__ float4 e1[64];  // dx/dd, dy/dd, dx/dy, by

    const int tid = threadIdx.x;
    const int b   = blockIdx.x >> 2;

    if (tid < 64) {
        const float2* vp = (const float2*)(verts + (b << 7));
        float2 a = vp[tid];
        float2 c = vp[(tid + 1) & 63];
        float dx = c.x - a.x, dy = c.y - a.y;
        float dd = fmaxf(fmaf(dx, dx, dy * dy), 1e-12f);
        float rdd = 1.0f / dd;
        e0[tid] = make_float4(a.x, a.y, dx, dy);
        e1[tid] = make_float4(dx * rdd, dy * rdd, dx / dy, c.y);
    }
    __syncthreads();

    const int row = ((blockIdx.x & 3) << 4) + (tid >> 4);  // 0..63
    const float py  = (float)row;
    const float pxb = (float)((tid & 15) << 2);

    float md0 = 1e30f, md1 = 1e30f, md2 = 1e30f, md3 = 1e30f;
    u64 pm0 = 0ull, pm1 = 0ull, pm2 = 0ull, pm3 = 0ull;

    #pragma unroll 4
    for (int n = 0; n < 64; n += 2) {
        const float4 A0 = e0[n],     A1 = e1[n];
        const float4 B0 = e0[n + 1], B1 = e1[n + 1];
        float dA0, dA1, dA2, dA3, dB0, dB1, dB2, dB3;
        {
            float pay  = py - A0.y;
            float pdyr = pay * A1.y;          // pay * dy/dd
            float xma  = pay * A1.z;          // pay * dx/dy  (vs pax)
            u64 cm = __ballot(A0.y > py) ^ __ballot(A1.w > py);
            float pax0 = pxb - A0.x, pax1 = pax0 + 1.0f,
                  pax2 = pax0 + 2.0f, pax3 = pax0 + 3.0f;
            float t0 = __builtin_amdgcn_fmed3f(fmaf(pax0, A1.x, pdyr), 0.f, 1.f);
            float t1 = __builtin_amdgcn_fmed3f(fmaf(pax1, A1.x, pdyr), 0.f, 1.f);
            float t2 = __builtin_amdgcn_fmed3f(fmaf(pax2, A1.x, pdyr), 0.f, 1.f);
            float t3 = __builtin_amdgcn_fmed3f(fmaf(pax3, A1.x, pdyr), 0.f, 1.f);
            float ex0 = fmaf(-t0, A0.z, pax0), ey0 = fmaf(-t0, A0.w, pay);
            float ex1 = fmaf(-t1, A0.z, pax1), ey1 = fmaf(-t1, A0.w, pay);
            float ex2 = fmaf(-t2, A0.z, pax2), ey2 = fmaf(-t2, A0.w, pay);
            float ex3 = fmaf(-t3, A0.z, pax3), ey3 = fmaf(-t3, A0.w, pay);
            dA0 = fmaf(ex0, ex0, ey0 * ey0);
            dA1 = fmaf(ex1, ex1, ey1 * ey1);
            dA2 = fmaf(ex2, ex2, ey2 * ey2);
            dA3 = fmaf(ex3, ex3, ey3 * ey3);
            pm0 ^= cm & __ballot(pax0 < xma);
            pm1 ^= cm & __ballot(pax1 < xma);
            pm2 ^= cm & __ballot(pax2 < xma);
            pm3 ^= cm & __ballot(pax3 < xma);
        }
        {
            float pay  = py - B0.y;
            float pdyr = pay * B1.y;
            float xma  = pay * B1.z;
            u64 cm = __ballot(B0.y > py) ^ __ballot(B1.w > py);
            float pax0 = pxb - B0.x, pax1 = pax0 + 1.0f,
                  pax2 = pax0 + 2.0f, pax3 = pax0 + 3.0f;
            float t0 = __builtin_amdgcn_fmed3f(fmaf(pax0, B1.x, pdyr), 0.f, 1.f);
            float t1 = __builtin_amdgcn_fmed3f(fmaf(pax1, B1.x, pdyr), 0.f, 1.f);
            float t2 = __builtin_amdgcn_fmed3f(fmaf(pax2, B1.x, pdyr), 0.f, 1.f);
            float t3 = __builtin_amdgcn_fmed3f(fmaf(pax3, B1.x, pdyr), 0.f, 1.f);
            float ex0 = fmaf(-t0, B0.z, pax0), ey0 = fmaf(-t0, B0.w, pay);
            float ex1 = fmaf(-t1, B0.z, pax1), ey1 = fmaf(-t1, B0.w, pay);
            float ex2 = fmaf(-t2, B0.z, pax2), ey2 = fmaf(-t2, B0.w, pay);
            float ex3 = fmaf(-t3, B0.z, pax3), ey3 = fmaf(-t3, B0.w, pay);
            dB0 = fmaf(ex0, ex0, ey0 * ey0);
            dB1 = fmaf(ex1, ex1, ey1 * ey1);
            dB2 = fmaf(ex2, ex2, ey2 * ey2);
            dB3 = fmaf(ex3, ex3, ey3 * ey3);
            pm0 ^= cm & __ballot(pax0 < xma);
            pm1 ^= cm & __ballot(pax1 < xma);
            pm2 ^= cm & __ballot(pax2 < xma);
            pm3 ^= cm & __ballot(pax3 < xma);
        }
        md0 = fminf(md0, fminf(dA0, dB0));  // -> v_min3_f32
        md1 = fminf(md1, fminf(dA1, dB1));
        md2 = fminf(md2, fminf(dA2, dB2));
        md3 = fminf(md3, fminf(dA3, dB3));
    }

    const int lane = tid & 63;
    const float s0 = ((pm0 >> lane) & 1ull) ? 10.0f : -10.0f;
    const float s1 = ((pm1 >> lane) & 1ull) ? 10.0f : -10.0f;
    const float s2 = ((pm2 >> lane) & 1ull) ? 10.0f : -10.0f;
    const float s3 = ((pm3 >> lane) & 1ull) ? 10.0f : -10.0f;
    float4 r;
    r.x = 1.0f / (1.0f + __expf(-s0 * md0));
    r.y = 1.0f / (1.0f + __expf(-s1 * md1));
    r.z = 1.0f / (1.0f + __expf(-s2 * md2));
    r.w = 1.0f / (1.0f + __expf(-s3 * md3));
    ((float4*)out)[(b << 10) + (row << 4) + (tid & 15)] = r;
}

extern "C" void kernel_launch(void* const* d_in, const int* in_sizes, int n_in,
                              void* d_out, int out_size, void* d_ws, size_t ws_size,
                              hipStream_t stream) {
    const float* verts = (const float*)d_in[0];
    float* out = (float*)d_out;
    const int B = out_size >> 12;  // 64*64 px per image
    softpoly_kernel<<<dim3(B * 4), dim3(256), 0, stream>>>(verts, out);
}